// Round 1
// baseline (2124.886 us; speedup 1.0000x reference)
//
#include <hip/hip_runtime.h>

#define N_NODES   100000
#define N_EDGES   600000
#define D_FEAT    128
#define N_CLASSES 40

// ---------------- degree / normalization ----------------

__global__ void k_deg_init(float* __restrict__ deg) {
    int i = blockIdx.x * blockDim.x + threadIdx.x;
    if (i < N_NODES) deg[i] = 1.0f;   // self-loop weight
}

__global__ void k_deg_count(const int* __restrict__ edst, float* __restrict__ deg) {
    int e = blockIdx.x * blockDim.x + threadIdx.x;
    if (e < N_EDGES) unsafeAtomicAdd(&deg[edst[e]], 1.0f);
}

__global__ void k_dinv(float* __restrict__ deg) {
    int i = blockIdx.x * blockDim.x + threadIdx.x;
    if (i < N_NODES) deg[i] = 1.0f / sqrtf(deg[i]);   // deg >= 1 always
}

// ---------------- propagation ----------------

// xout[i] = xin[i] * dinv[i]^2   (self-loop term; full overwrite -> re-inits ws)
__global__ void k_selfinit(const float* __restrict__ xin, float* __restrict__ xout,
                           const float* __restrict__ dinv) {
    int idx = blockIdx.x * blockDim.x + threadIdx.x;   // one thread per float4
    if (idx >= N_NODES * (D_FEAT / 4)) return;
    int node = idx >> 5;
    float s = dinv[node];
    s = s * s;
    float4 v = ((const float4*)xin)[idx];
    v.x *= s; v.y *= s; v.z *= s; v.w *= s;
    ((float4*)xout)[idx] = v;
}

// xout[dst] += xin[src] * dinv[src]*dinv[dst]   (32 lanes per edge, float4 each)
__global__ void k_scatter(const float* __restrict__ xin, float* __restrict__ xout,
                          const float* __restrict__ dinv,
                          const int* __restrict__ esrc, const int* __restrict__ edst) {
    int t = blockIdx.x * blockDim.x + threadIdx.x;
    int e = t >> 5;
    int lane = t & 31;
    if (e >= N_EDGES) return;
    int s = esrc[e];
    int d = edst[e];
    float nrm = dinv[s] * dinv[d];
    float4 v = ((const float4*)(xin + (size_t)s * D_FEAT))[lane];
    float* o = xout + (size_t)d * D_FEAT + lane * 4;
    unsafeAtomicAdd(o + 0, v.x * nrm);
    unsafeAtomicAdd(o + 1, v.y * nrm);
    unsafeAtomicAdd(o + 2, v.z * nrm);
    unsafeAtomicAdd(o + 3, v.w * nrm);
}

// ---------------- classifier + log_softmax ----------------

#define CHUNK 64
#define WROW  132   // padded row: bank-conflict-free LDS reads

__global__ __launch_bounds__(256) void k_classify(const float* __restrict__ x,
                                                  const float* __restrict__ W,
                                                  const float* __restrict__ b,
                                                  float* __restrict__ out) {
    __shared__ float Wl[N_CLASSES][WROW];
    __shared__ float xl[CHUNK][WROW];
    __shared__ float bl[N_CLASSES];
    int t = threadIdx.x;

    // stage W (40x128) as float4
    for (int f = t; f < N_CLASSES * (D_FEAT / 4); f += 256) {
        int c = f >> 5, d4 = f & 31;
        float4 w = ((const float4*)W)[f];
        *(float4*)&Wl[c][d4 * 4] = w;
    }
    if (t < N_CLASSES) bl[t] = b[t];

    int n0 = blockIdx.x * CHUNK;
    // stage x tile (64x128) as float4, coalesced
    for (int f = t; f < CHUNK * (D_FEAT / 4); f += 256) {
        int n = f >> 5, d4 = f & 31;
        float4 v = make_float4(0.f, 0.f, 0.f, 0.f);
        if (n0 + n < N_NODES) v = ((const float4*)(x + (size_t)(n0 + n) * D_FEAT))[d4];
        *(float4*)&xl[n][d4 * 4] = v;
    }
    __syncthreads();

    int n = t >> 2;          // local node 0..63
    int sub = t & 3;         // 4 threads per node
    int c0 = sub * 10;       // 10 classes per thread

    float acc[10];
#pragma unroll
    for (int j = 0; j < 10; ++j) acc[j] = 0.f;

    for (int d4 = 0; d4 < D_FEAT / 4; ++d4) {
        float4 xv = *(const float4*)&xl[n][d4 * 4];
#pragma unroll
        for (int j = 0; j < 10; ++j) {
            float4 wv = *(const float4*)&Wl[c0 + j][d4 * 4];
            acc[j] += xv.x * wv.x + xv.y * wv.y + xv.z * wv.z + xv.w * wv.w;
        }
    }

    float m = -INFINITY;
#pragma unroll
    for (int j = 0; j < 10; ++j) {
        acc[j] += bl[c0 + j];
        m = fmaxf(m, acc[j]);
    }
    m = fmaxf(m, __shfl_xor(m, 1, 4));
    m = fmaxf(m, __shfl_xor(m, 2, 4));
    float s = 0.f;
#pragma unroll
    for (int j = 0; j < 10; ++j) s += __expf(acc[j] - m);
    s += __shfl_xor(s, 1, 4);
    s += __shfl_xor(s, 2, 4);
    float lse = __logf(s) + m;

    if (n0 + n < N_NODES) {
        float* o = out + (size_t)(n0 + n) * N_CLASSES + c0;
#pragma unroll
        for (int j = 0; j < 10; ++j) o[j] = acc[j] - lse;
    }
}

// ---------------- launch ----------------

extern "C" void kernel_launch(void* const* d_in, const int* in_sizes, int n_in,
                              void* d_out, int out_size, void* d_ws, size_t ws_size,
                              hipStream_t stream) {
    const float* x   = (const float*)d_in[0];
    const int*   ei  = (const int*)d_in[1];          // [2, N_EDGES] row-major
    const float* W   = (const float*)d_in[2];
    const float* b   = (const float*)d_in[3];
    float*       out = (float*)d_out;

    const int* esrc = ei;
    const int* edst = ei + N_EDGES;

    // workspace layout (floats): dinv[100000] | x1[12.8M] | x2[12.8M]  (~98 MB)
    float* base = (float*)d_ws;
    float* dinv = base;
    float* x1   = base + 100352;          // 64-float aligned
    float* x2   = x1 + (size_t)N_NODES * D_FEAT;

    const int B = 256;
    // 1. degrees -> dinv
    k_deg_init<<<(N_NODES + B - 1) / B, B, 0, stream>>>(dinv);
    k_deg_count<<<(N_EDGES + B - 1) / B, B, 0, stream>>>(edst, dinv);
    k_dinv<<<(N_NODES + B - 1) / B, B, 0, stream>>>(dinv);

    const int selfinit_grid = (N_NODES * (D_FEAT / 4) + B - 1) / B;   // 12500
    const int scatter_grid  = (N_EDGES * 32) / B;                      // 75000

    // 2. round 1: x -> x1
    k_selfinit<<<selfinit_grid, B, 0, stream>>>(x, x1, dinv);
    k_scatter<<<scatter_grid, B, 0, stream>>>(x, x1, dinv, esrc, edst);

    // 3. round 2: x1 -> x2
    k_selfinit<<<selfinit_grid, B, 0, stream>>>(x1, x2, dinv);
    k_scatter<<<scatter_grid, B, 0, stream>>>(x1, x2, dinv, esrc, edst);

    // 4. classifier + log_softmax
    k_classify<<<(N_NODES + CHUNK - 1) / CHUNK, B, 0, stream>>>(x2, W, b, out);
}

// Round 2
// 289.950 us; speedup vs baseline: 7.3285x; 7.3285x over previous
//
#include <hip/hip_runtime.h>

#define N_NODES   100000
#define N_EDGES   600000
#define D_FEAT    128
#define N_CLASSES 40

// ================= CSR build =================

__global__ void k_zero(int* __restrict__ deg) {
    int i = blockIdx.x * blockDim.x + threadIdx.x;
    if (i < N_NODES) deg[i] = 0;
}

__global__ void k_count(const int* __restrict__ edst, int* __restrict__ deg) {
    int e = blockIdx.x * blockDim.x + threadIdx.x;
    if (e < N_EDGES) atomicAdd(&deg[edst[e]], 1);
}

// single-block exclusive scan over deg -> row_ptr; also cursor copy and dinv
__global__ __launch_bounds__(1024) void k_scan(const int* __restrict__ deg,
                                               int* __restrict__ row_ptr,
                                               int* __restrict__ cursor,
                                               float* __restrict__ dinv) {
    __shared__ int wsum[16];
    int t = threadIdx.x;
    int lane = t & 63, w = t >> 6;
    int running = 0;
    for (int base = 0; base < N_NODES; base += 1024) {
        int i = base + t;
        int v = (i < N_NODES) ? deg[i] : 0;
        int x = v;
#pragma unroll
        for (int d = 1; d < 64; d <<= 1) {
            int y = __shfl_up(x, d, 64);
            if (lane >= d) x += y;
        }
        if (lane == 63) wsum[w] = x;
        __syncthreads();
        if (t < 16) {
            int s = wsum[t];
#pragma unroll
            for (int d = 1; d < 16; d <<= 1) {
                int y = __shfl_up(s, d, 16);
                if (t >= d) s += y;
            }
            wsum[t] = s;   // inclusive over wave sums
        }
        __syncthreads();
        int waveoff = (w == 0) ? 0 : wsum[w - 1];
        int excl = running + waveoff + (x - v);
        if (i < N_NODES) {
            row_ptr[i] = excl;
            cursor[i]  = excl;
            dinv[i]    = rsqrtf((float)(v + 1));   // +1 self-loop
        }
        running += wsum[15];
        __syncthreads();   // wsum reused next iteration
    }
    if (t == 0) row_ptr[N_NODES] = running;
}

__global__ void k_fill(const int* __restrict__ esrc, const int* __restrict__ edst,
                       int* __restrict__ cursor, int* __restrict__ csr_src) {
    int e = blockIdx.x * blockDim.x + threadIdx.x;
    if (e < N_EDGES) {
        int d = edst[e];
        int pos = atomicAdd(&cursor[d], 1);
        csr_src[pos] = esrc[e];
    }
}

// ================= y0 = x @ W^T  (no bias) =================

#define CHUNK 64
#define WROW  132

__global__ __launch_bounds__(256) void k_gemm(const float* __restrict__ x,
                                              const float* __restrict__ W,
                                              float* __restrict__ y) {
    __shared__ float Wl[N_CLASSES][WROW];
    __shared__ float xl[CHUNK][WROW];
    int t = threadIdx.x;

    for (int f = t; f < N_CLASSES * (D_FEAT / 4); f += 256) {
        int c = f >> 5, d4 = f & 31;
        float4 w = ((const float4*)W)[f];
        *(float4*)&Wl[c][d4 * 4] = w;
    }

    int n0 = blockIdx.x * CHUNK;
    for (int f = t; f < CHUNK * (D_FEAT / 4); f += 256) {
        int n = f >> 5, d4 = f & 31;
        float4 v = make_float4(0.f, 0.f, 0.f, 0.f);
        if (n0 + n < N_NODES) v = ((const float4*)(x + (size_t)(n0 + n) * D_FEAT))[d4];
        *(float4*)&xl[n][d4 * 4] = v;
    }
    __syncthreads();

    int n = t >> 2;
    int sub = t & 3;
    int c0 = sub * 10;

    float acc[10];
#pragma unroll
    for (int j = 0; j < 10; ++j) acc[j] = 0.f;

    for (int d4 = 0; d4 < D_FEAT / 4; ++d4) {
        float4 xv = *(const float4*)&xl[n][d4 * 4];
#pragma unroll
        for (int j = 0; j < 10; ++j) {
            float4 wv = *(const float4*)&Wl[c0 + j][d4 * 4];
            acc[j] += xv.x * wv.x + xv.y * wv.y + xv.z * wv.z + xv.w * wv.w;
        }
    }

    if (n0 + n < N_NODES) {
        float* o = y + (size_t)(n0 + n) * N_CLASSES + c0;
#pragma unroll
        for (int j = 0; j < 10; ++j) o[j] = acc[j];
    }
}

// ================= CSR gather propagation (40-wide) =================

__global__ __launch_bounds__(256) void k_gather(const float* __restrict__ yin,
                                                float* __restrict__ yout,
                                                const float* __restrict__ dinv,
                                                const int* __restrict__ row_ptr,
                                                const int* __restrict__ csr_src) {
    int i = blockIdx.x * blockDim.x + threadIdx.x;
    if (i >= N_NODES) return;
    float di = dinv[i];
    float s2 = di * di;
    float4 a[10];
    const float4* self = (const float4*)(yin + (size_t)i * N_CLASSES);
#pragma unroll
    for (int r = 0; r < 10; ++r) {
        float4 v = self[r];
        a[r] = make_float4(v.x * s2, v.y * s2, v.z * s2, v.w * s2);
    }
    int e = row_ptr[i], end = row_ptr[i + 1];
    for (; e < end; ++e) {
        int s = csr_src[e];
        float nrm = di * dinv[s];
        const float4* ys = (const float4*)(yin + (size_t)s * N_CLASSES);
#pragma unroll
        for (int r = 0; r < 10; ++r) {
            float4 v = ys[r];
            a[r].x += v.x * nrm; a[r].y += v.y * nrm;
            a[r].z += v.z * nrm; a[r].w += v.w * nrm;
        }
    }
    float4* o = (float4*)(yout + (size_t)i * N_CLASSES);
#pragma unroll
    for (int r = 0; r < 10; ++r) o[r] = a[r];
}

// round 2 fused with bias + log_softmax
__global__ __launch_bounds__(256) void k_gather_out(const float* __restrict__ yin,
                                                    float* __restrict__ out,
                                                    const float* __restrict__ dinv,
                                                    const int* __restrict__ row_ptr,
                                                    const int* __restrict__ csr_src,
                                                    const float* __restrict__ bias) {
    int i = blockIdx.x * blockDim.x + threadIdx.x;
    if (i >= N_NODES) return;
    float di = dinv[i];
    float s2 = di * di;
    float4 a[10];
    const float4* self = (const float4*)(yin + (size_t)i * N_CLASSES);
#pragma unroll
    for (int r = 0; r < 10; ++r) {
        float4 v = self[r];
        a[r] = make_float4(v.x * s2, v.y * s2, v.z * s2, v.w * s2);
    }
    int e = row_ptr[i], end = row_ptr[i + 1];
    for (; e < end; ++e) {
        int s = csr_src[e];
        float nrm = di * dinv[s];
        const float4* ys = (const float4*)(yin + (size_t)s * N_CLASSES);
#pragma unroll
        for (int r = 0; r < 10; ++r) {
            float4 v = ys[r];
            a[r].x += v.x * nrm; a[r].y += v.y * nrm;
            a[r].z += v.z * nrm; a[r].w += v.w * nrm;
        }
    }
    const float4* b4 = (const float4*)bias;
    float m = -INFINITY;
#pragma unroll
    for (int r = 0; r < 10; ++r) {
        float4 b = b4[r];
        a[r].x += b.x; a[r].y += b.y; a[r].z += b.z; a[r].w += b.w;
        m = fmaxf(m, fmaxf(fmaxf(a[r].x, a[r].y), fmaxf(a[r].z, a[r].w)));
    }
    float s = 0.f;
#pragma unroll
    for (int r = 0; r < 10; ++r) {
        s += __expf(a[r].x - m) + __expf(a[r].y - m)
           + __expf(a[r].z - m) + __expf(a[r].w - m);
    }
    float lse = __logf(s) + m;
    float4* o = (float4*)(out + (size_t)i * N_CLASSES);
#pragma unroll
    for (int r = 0; r < 10; ++r) {
        o[r] = make_float4(a[r].x - lse, a[r].y - lse, a[r].z - lse, a[r].w - lse);
    }
}

// ================= launch =================

extern "C" void kernel_launch(void* const* d_in, const int* in_sizes, int n_in,
                              void* d_out, int out_size, void* d_ws, size_t ws_size,
                              hipStream_t stream) {
    const float* x   = (const float*)d_in[0];
    const int*   ei  = (const int*)d_in[1];
    const float* W   = (const float*)d_in[2];
    const float* b   = (const float*)d_in[3];
    float*       out = (float*)d_out;

    const int* esrc = ei;
    const int* edst = ei + N_EDGES;

    // workspace layout (4-byte elems, 16B-aligned sections)
    int*   deg     = (int*)d_ws;                       // 100096
    int*   row_ptr = deg + 100096;                     // 100096 (needs 100001)
    int*   cursor  = row_ptr + 100096;                 // 100096
    int*   csr_src = cursor + 100096;                  // 600064
    float* dinv    = (float*)(csr_src + 600064);       // 100096
    float* y0      = dinv + 100096;                    // 4,000,000
    float* z1      = y0 + (size_t)N_NODES * N_CLASSES; // 4,000,000

    const int B = 256;
    const int gN = (N_NODES + B - 1) / B;   // 391
    const int gE = (N_EDGES + B - 1) / B;   // 2344

    k_zero <<<gN, B, 0, stream>>>(deg);
    k_count<<<gE, B, 0, stream>>>(edst, deg);
    k_scan <<<1, 1024, 0, stream>>>(deg, row_ptr, cursor, dinv);
    k_fill <<<gE, B, 0, stream>>>(esrc, edst, cursor, csr_src);

    k_gemm<<<(N_NODES + CHUNK - 1) / CHUNK, B, 0, stream>>>(x, W, y0);

    k_gather    <<<gN, B, 0, stream>>>(y0, z1, dinv, row_ptr, csr_src);
    k_gather_out<<<gN, B, 0, stream>>>(z1, out, dinv, row_ptr, csr_src, b);
}

// Round 3
// 202.587 us; speedup vs baseline: 10.4887x; 1.4312x over previous
//
#include <hip/hip_runtime.h>

#define N_NODES   100000
#define N_EDGES   600000
#define D_FEAT    128
#define N_CLASSES 40

#define NPAD      100352            // N_NODES padded to 1024 multiple
#define SCAN_NBLK (NPAD / 1024)     // 98

// ================= CSR build =================

__global__ void k_zero(int* __restrict__ deg) {
    int i = blockIdx.x * blockDim.x + threadIdx.x;
    if (i < NPAD) deg[i] = 0;       // zero padding too (scan reads it)
}

__global__ void k_count(const int* __restrict__ edst, int* __restrict__ deg) {
    int e = blockIdx.x * blockDim.x + threadIdx.x;
    if (e < N_EDGES) atomicAdd(&deg[edst[e]], 1);
}

// phase 1: per-block exclusive scan (1024 elems/block), local prefixes -> row_ptr
__global__ __launch_bounds__(256) void k_scan1(const int* __restrict__ deg,
                                               int* __restrict__ row_ptr,
                                               int* __restrict__ blksum) {
    __shared__ int wsum[4];
    int t = threadIdx.x;
    int lane = t & 63, w = t >> 6;
    int base = blockIdx.x * 1024 + t * 4;
    int4 v = *(const int4*)(deg + base);
    int s0 = v.x, s1 = s0 + v.y, s2 = s1 + v.z, s3 = s2 + v.w;
    int inc = s3;
#pragma unroll
    for (int d = 1; d < 64; d <<= 1) {
        int y = __shfl_up(inc, d, 64);
        if (lane >= d) inc += y;
    }
    if (lane == 63) wsum[w] = inc;
    __syncthreads();
    int woff = 0;
#pragma unroll
    for (int j = 0; j < 3; ++j) woff += (j < w) ? wsum[j] : 0;
    int texcl = woff + inc - s3;
    int4 o;
    o.x = texcl;
    o.y = texcl + s0;
    o.z = texcl + s1;
    o.w = texcl + s2;
    *(int4*)(row_ptr + base) = o;
    if (t == 255) blksum[blockIdx.x] = woff + inc;   // block total
}

// phase 2: add block offsets in place; emit cursor + dinv
__global__ __launch_bounds__(256) void k_scan2(const int* __restrict__ deg,
                                               int* __restrict__ row_ptr,
                                               int* __restrict__ cursor,
                                               float* __restrict__ dinv,
                                               const int* __restrict__ blksum) {
    __shared__ int s[SCAN_NBLK];
    int t = threadIdx.x;
    int blk = blockIdx.x;
    if (t < SCAN_NBLK) s[t] = blksum[t];
    __syncthreads();
    int off = 0;
    for (int j = 0; j < blk; ++j) off += s[j];
    int base = blk * 1024 + t * 4;
    int4 v = *(int4*)(row_ptr + base);
    v.x += off; v.y += off; v.z += off; v.w += off;
    *(int4*)(row_ptr + base) = v;
    *(int4*)(cursor + base) = v;
    int4 d = *(const int4*)(deg + base);
    float4 di;
    di.x = rsqrtf((float)(d.x + 1));
    di.y = rsqrtf((float)(d.y + 1));
    di.z = rsqrtf((float)(d.z + 1));
    di.w = rsqrtf((float)(d.w + 1));
    *(float4*)(dinv + base) = di;
    // row_ptr[N_NODES] = 600000 falls out of the scan (deg padding is zero)
}

__global__ void k_fill(const int* __restrict__ esrc, const int* __restrict__ edst,
                       int* __restrict__ cursor, int* __restrict__ csr_src) {
    int e = blockIdx.x * blockDim.x + threadIdx.x;
    if (e < N_EDGES) {
        int d = edst[e];
        int pos = atomicAdd(&cursor[d], 1);
        csr_src[pos] = esrc[e];
    }
}

// ================= y0 = x @ W^T  (no bias) =================

#define CHUNK 64
#define WROW  132

__global__ __launch_bounds__(256) void k_gemm(const float* __restrict__ x,
                                              const float* __restrict__ W,
                                              float* __restrict__ y) {
    __shared__ float Wl[N_CLASSES][WROW];
    __shared__ float xl[CHUNK][WROW];
    int t = threadIdx.x;

    for (int f = t; f < N_CLASSES * (D_FEAT / 4); f += 256) {
        int c = f >> 5, d4 = f & 31;
        float4 w = ((const float4*)W)[f];
        *(float4*)&Wl[c][d4 * 4] = w;
    }

    int n0 = blockIdx.x * CHUNK;
    for (int f = t; f < CHUNK * (D_FEAT / 4); f += 256) {
        int n = f >> 5, d4 = f & 31;
        float4 v = make_float4(0.f, 0.f, 0.f, 0.f);
        if (n0 + n < N_NODES) v = ((const float4*)(x + (size_t)(n0 + n) * D_FEAT))[d4];
        *(float4*)&xl[n][d4 * 4] = v;
    }
    __syncthreads();

    int n = t >> 2;
    int sub = t & 3;
    int c0 = sub * 10;

    float acc[10];
#pragma unroll
    for (int j = 0; j < 10; ++j) acc[j] = 0.f;

    for (int d4 = 0; d4 < D_FEAT / 4; ++d4) {
        float4 xv = *(const float4*)&xl[n][d4 * 4];
#pragma unroll
        for (int j = 0; j < 10; ++j) {
            float4 wv = *(const float4*)&Wl[c0 + j][d4 * 4];
            acc[j] += xv.x * wv.x + xv.y * wv.y + xv.z * wv.z + xv.w * wv.w;
        }
    }

    if (n0 + n < N_NODES) {
        float* o = y + (size_t)(n0 + n) * N_CLASSES + c0;
#pragma unroll
        for (int j = 0; j < 10; ++j) o[j] = acc[j];
    }
}

// ================= CSR gather propagation (40-wide) =================

__global__ __launch_bounds__(256) void k_gather(const float* __restrict__ yin,
                                                float* __restrict__ yout,
                                                const float* __restrict__ dinv,
                                                const int* __restrict__ row_ptr,
                                                const int* __restrict__ csr_src) {
    int i = blockIdx.x * blockDim.x + threadIdx.x;
    if (i >= N_NODES) return;
    float di = dinv[i];
    float s2 = di * di;
    float4 a[10];
    const float4* self = (const float4*)(yin + (size_t)i * N_CLASSES);
#pragma unroll
    for (int r = 0; r < 10; ++r) {
        float4 v = self[r];
        a[r] = make_float4(v.x * s2, v.y * s2, v.z * s2, v.w * s2);
    }
    int e = row_ptr[i], end = row_ptr[i + 1];
    for (; e < end; ++e) {
        int s = csr_src[e];
        float nrm = di * dinv[s];
        const float4* ys = (const float4*)(yin + (size_t)s * N_CLASSES);
#pragma unroll
        for (int r = 0; r < 10; ++r) {
            float4 v = ys[r];
            a[r].x += v.x * nrm; a[r].y += v.y * nrm;
            a[r].z += v.z * nrm; a[r].w += v.w * nrm;
        }
    }
    float4* o = (float4*)(yout + (size_t)i * N_CLASSES);
#pragma unroll
    for (int r = 0; r < 10; ++r) o[r] = a[r];
}

// round 2 fused with bias + log_softmax
__global__ __launch_bounds__(256) void k_gather_out(const float* __restrict__ yin,
                                                    float* __restrict__ out,
                                                    const float* __restrict__ dinv,
                                                    const int* __restrict__ row_ptr,
                                                    const int* __restrict__ csr_src,
                                                    const float* __restrict__ bias) {
    int i = blockIdx.x * blockDim.x + threadIdx.x;
    if (i >= N_NODES) return;
    float di = dinv[i];
    float s2 = di * di;
    float4 a[10];
    const float4* self = (const float4*)(yin + (size_t)i * N_CLASSES);
#pragma unroll
    for (int r = 0; r < 10; ++r) {
        float4 v = self[r];
        a[r] = make_float4(v.x * s2, v.y * s2, v.z * s2, v.w * s2);
    }
    int e = row_ptr[i], end = row_ptr[i + 1];
    for (; e < end; ++e) {
        int s = csr_src[e];
        float nrm = di * dinv[s];
        const float4* ys = (const float4*)(yin + (size_t)s * N_CLASSES);
#pragma unroll
        for (int r = 0; r < 10; ++r) {
            float4 v = ys[r];
            a[r].x += v.x * nrm; a[r].y += v.y * nrm;
            a[r].z += v.z * nrm; a[r].w += v.w * nrm;
        }
    }
    const float4* b4 = (const float4*)bias;
    float m = -INFINITY;
#pragma unroll
    for (int r = 0; r < 10; ++r) {
        float4 b = b4[r];
        a[r].x += b.x; a[r].y += b.y; a[r].z += b.z; a[r].w += b.w;
        m = fmaxf(m, fmaxf(fmaxf(a[r].x, a[r].y), fmaxf(a[r].z, a[r].w)));
    }
    float s = 0.f;
#pragma unroll
    for (int r = 0; r < 10; ++r) {
        s += __expf(a[r].x - m) + __expf(a[r].y - m)
           + __expf(a[r].z - m) + __expf(a[r].w - m);
    }
    float lse = __logf(s) + m;
    float4* o = (float4*)(out + (size_t)i * N_CLASSES);
#pragma unroll
    for (int r = 0; r < 10; ++r) {
        o[r] = make_float4(a[r].x - lse, a[r].y - lse, a[r].z - lse, a[r].w - lse);
    }
}

// ================= launch =================

extern "C" void kernel_launch(void* const* d_in, const int* in_sizes, int n_in,
                              void* d_out, int out_size, void* d_ws, size_t ws_size,
                              hipStream_t stream) {
    const float* x   = (const float*)d_in[0];
    const int*   ei  = (const int*)d_in[1];
    const float* W   = (const float*)d_in[2];
    const float* b   = (const float*)d_in[3];
    float*       out = (float*)d_out;

    const int* esrc = ei;
    const int* edst = ei + N_EDGES;

    // workspace layout (4-byte elems, 16B-aligned sections)
    int*   deg     = (int*)d_ws;                       // NPAD
    int*   row_ptr = deg + NPAD;                       // NPAD (covers N_NODES+1)
    int*   cursor  = row_ptr + NPAD;                   // NPAD
    int*   blksum  = cursor + NPAD;                    // 128
    int*   csr_src = blksum + 128;                     // 600064
    float* dinv    = (float*)(csr_src + 600064);       // NPAD
    float* y0      = dinv + NPAD;                      // 4,000,000
    float* z1      = y0 + (size_t)N_NODES * N_CLASSES; // 4,000,000

    const int B = 256;
    const int gP = (NPAD + B - 1) / B;      // 392
    const int gN = (N_NODES + B - 1) / B;   // 391
    const int gE = (N_EDGES + B - 1) / B;   // 2344

    k_zero <<<gP, B, 0, stream>>>(deg);
    k_count<<<gE, B, 0, stream>>>(edst, deg);
    k_scan1<<<SCAN_NBLK, B, 0, stream>>>(deg, row_ptr, blksum);
    k_scan2<<<SCAN_NBLK, B, 0, stream>>>(deg, row_ptr, cursor, dinv, blksum);
    k_fill <<<gE, B, 0, stream>>>(esrc, edst, cursor, csr_src);

    k_gemm<<<(N_NODES + CHUNK - 1) / CHUNK, B, 0, stream>>>(x, W, y0);

    k_gather    <<<gN, B, 0, stream>>>(y0, z1, dinv, row_ptr, csr_src);
    k_gather_out<<<gN, B, 0, stream>>>(z1, out, dinv, row_ptr, csr_src, b);
}

// Round 4
// 179.255 us; speedup vs baseline: 11.8540x; 1.1302x over previous
//
#include <hip/hip_runtime.h>

#define N_NODES   100000
#define N_EDGES   600000
#define D_FEAT    128
#define N_CLASSES 40

#define NPAD      100352            // N_NODES padded to 1024 multiple
#define SCAN_NBLK (NPAD / 1024)     // 98

// ================= CSR build =================

__global__ void k_count(const int* __restrict__ edst, int* __restrict__ deg) {
    int e = blockIdx.x * blockDim.x + threadIdx.x;
    if (e < N_EDGES) atomicAdd(&deg[edst[e]], 1);
}

// phase 1: per-block exclusive scan (1024 elems/block), local prefixes -> row_ptr
__global__ __launch_bounds__(256) void k_scan1(const int* __restrict__ deg,
                                               int* __restrict__ row_ptr,
                                               int* __restrict__ blksum) {
    __shared__ int wsum[4];
    int t = threadIdx.x;
    int lane = t & 63, w = t >> 6;
    int base = blockIdx.x * 1024 + t * 4;
    int4 v = *(const int4*)(deg + base);
    int s0 = v.x, s1 = s0 + v.y, s2 = s1 + v.z, s3 = s2 + v.w;
    int inc = s3;
#pragma unroll
    for (int d = 1; d < 64; d <<= 1) {
        int y = __shfl_up(inc, d, 64);
        if (lane >= d) inc += y;
    }
    if (lane == 63) wsum[w] = inc;
    __syncthreads();
    int woff = 0;
#pragma unroll
    for (int j = 0; j < 3; ++j) woff += (j < w) ? wsum[j] : 0;
    int texcl = woff + inc - s3;
    int4 o;
    o.x = texcl;
    o.y = texcl + s0;
    o.z = texcl + s1;
    o.w = texcl + s2;
    *(int4*)(row_ptr + base) = o;
    if (t == 255) blksum[blockIdx.x] = woff + inc;   // block total
}

// phase 2: add block offsets in place; emit cursor + dinv
__global__ __launch_bounds__(256) void k_scan2(const int* __restrict__ deg,
                                               int* __restrict__ row_ptr,
                                               int* __restrict__ cursor,
                                               float* __restrict__ dinv,
                                               const int* __restrict__ blksum) {
    __shared__ int s[SCAN_NBLK];
    int t = threadIdx.x;
    int blk = blockIdx.x;
    if (t < SCAN_NBLK) s[t] = blksum[t];
    __syncthreads();
    int off = 0;
    for (int j = 0; j < blk; ++j) off += s[j];
    int base = blk * 1024 + t * 4;
    int4 v = *(int4*)(row_ptr + base);
    v.x += off; v.y += off; v.z += off; v.w += off;
    *(int4*)(row_ptr + base) = v;
    *(int4*)(cursor + base) = v;
    int4 d = *(const int4*)(deg + base);
    float4 di;
    di.x = rsqrtf((float)(d.x + 1));
    di.y = rsqrtf((float)(d.y + 1));
    di.z = rsqrtf((float)(d.z + 1));
    di.w = rsqrtf((float)(d.w + 1));
    *(float4*)(dinv + base) = di;
    // row_ptr[N_NODES] = 600000 falls out of the scan (deg padding is zero)
}

__global__ void k_fill(const int* __restrict__ esrc, const int* __restrict__ edst,
                       int* __restrict__ cursor, int* __restrict__ csr_src) {
    int e = blockIdx.x * blockDim.x + threadIdx.x;
    if (e < N_EDGES) {
        int d = edst[e];
        int pos = atomicAdd(&cursor[d], 1);
        csr_src[pos] = esrc[e];
    }
}

// ================= u0 = (x @ W^T) * dinv[node]  =================
// 256 threads = 64 nodes/block, 4 threads/node x 10 classes each.
// x read directly from global (quad-broadcast via L1); only W staged in LDS.

#define WROW 132

__global__ __launch_bounds__(256) void k_gemm(const float* __restrict__ x,
                                              const float* __restrict__ W,
                                              const float* __restrict__ dinv,
                                              float* __restrict__ y) {
    __shared__ float Wl[N_CLASSES][WROW];
    int t = threadIdx.x;

    for (int f = t; f < N_CLASSES * (D_FEAT / 4); f += 256) {
        int c = f >> 5, d4 = f & 31;
        float4 w = ((const float4*)W)[f];
        *(float4*)&Wl[c][d4 * 4] = w;
    }
    __syncthreads();

    int node = blockIdx.x * 64 + (t >> 2);
    if (node >= N_NODES) return;
    int sub = t & 3;
    int c0 = sub * 10;

    const float4* xp = (const float4*)(x + (size_t)node * D_FEAT);

    float acc[10];
#pragma unroll
    for (int j = 0; j < 10; ++j) acc[j] = 0.f;

    for (int d4 = 0; d4 < D_FEAT / 4; ++d4) {
        float4 xv = xp[d4];
#pragma unroll
        for (int j = 0; j < 10; ++j) {
            float4 wv = *(const float4*)&Wl[c0 + j][d4 * 4];
            acc[j] += xv.x * wv.x + xv.y * wv.y + xv.z * wv.z + xv.w * wv.w;
        }
    }

    float di = dinv[node];
    float* o = y + (size_t)node * N_CLASSES + c0;
#pragma unroll
    for (int j = 0; j < 10; ++j) o[j] = acc[j] * di;
}

// ================= CSR gather propagation on u (2 threads/node) =================
// u_out[d] = dinv[d]^2 * ( u_in[d] + sum_{s in N(d)} u_in[s] )

__global__ __launch_bounds__(256) void k_gather(const float* __restrict__ yin,
                                                float* __restrict__ yout,
                                                const float* __restrict__ dinv,
                                                const int* __restrict__ row_ptr,
                                                const int* __restrict__ csr_src) {
    int t = blockIdx.x * blockDim.x + threadIdx.x;
    int i = t >> 1;
    if (i >= N_NODES) return;
    int sub = t & 1;                    // half-row: float4s [sub*5, sub*5+5)
    const float4* yb = (const float4*)yin;
    const float4* self = yb + (size_t)i * 10 + sub * 5;
    float4 a0 = self[0], a1 = self[1], a2 = self[2], a3 = self[3], a4 = self[4];

    int e = row_ptr[i], end = row_ptr[i + 1];
    for (; e + 2 <= end; e += 2) {
        int s0 = csr_src[e], s1 = csr_src[e + 1];
        const float4* p0 = yb + (size_t)s0 * 10 + sub * 5;
        const float4* p1 = yb + (size_t)s1 * 10 + sub * 5;
        float4 v00 = p0[0], v01 = p0[1], v02 = p0[2], v03 = p0[3], v04 = p0[4];
        float4 v10 = p1[0], v11 = p1[1], v12 = p1[2], v13 = p1[3], v14 = p1[4];
        a0.x += v00.x + v10.x; a0.y += v00.y + v10.y; a0.z += v00.z + v10.z; a0.w += v00.w + v10.w;
        a1.x += v01.x + v11.x; a1.y += v01.y + v11.y; a1.z += v01.z + v11.z; a1.w += v01.w + v11.w;
        a2.x += v02.x + v12.x; a2.y += v02.y + v12.y; a2.z += v02.z + v12.z; a2.w += v02.w + v12.w;
        a3.x += v03.x + v13.x; a3.y += v03.y + v13.y; a3.z += v03.z + v13.z; a3.w += v03.w + v13.w;
        a4.x += v04.x + v14.x; a4.y += v04.y + v14.y; a4.z += v04.z + v14.z; a4.w += v04.w + v14.w;
    }
    if (e < end) {
        int s0 = csr_src[e];
        const float4* p0 = yb + (size_t)s0 * 10 + sub * 5;
        float4 v00 = p0[0], v01 = p0[1], v02 = p0[2], v03 = p0[3], v04 = p0[4];
        a0.x += v00.x; a0.y += v00.y; a0.z += v00.z; a0.w += v00.w;
        a1.x += v01.x; a1.y += v01.y; a1.z += v01.z; a1.w += v01.w;
        a2.x += v02.x; a2.y += v02.y; a2.z += v02.z; a2.w += v02.w;
        a3.x += v03.x; a3.y += v03.y; a3.z += v03.z; a3.w += v03.w;
        a4.x += v04.x; a4.y += v04.y; a4.z += v04.z; a4.w += v04.w;
    }

    float di = dinv[i];
    float s2 = di * di;
    float4* o = (float4*)yout + (size_t)i * 10 + sub * 5;
    o[0] = make_float4(a0.x * s2, a0.y * s2, a0.z * s2, a0.w * s2);
    o[1] = make_float4(a1.x * s2, a1.y * s2, a1.z * s2, a1.w * s2);
    o[2] = make_float4(a2.x * s2, a2.y * s2, a2.z * s2, a2.w * s2);
    o[3] = make_float4(a3.x * s2, a3.y * s2, a3.z * s2, a3.w * s2);
    o[4] = make_float4(a4.x * s2, a4.y * s2, a4.z * s2, a4.w * s2);
}

// final round: logits = dinv[d]*v + b, then log_softmax (pair of lanes cooperates)
__global__ __launch_bounds__(256) void k_gather_out(const float* __restrict__ yin,
                                                    float* __restrict__ out,
                                                    const float* __restrict__ dinv,
                                                    const int* __restrict__ row_ptr,
                                                    const int* __restrict__ csr_src,
                                                    const float* __restrict__ bias) {
    int t = blockIdx.x * blockDim.x + threadIdx.x;
    int i = t >> 1;
    if (i >= N_NODES) return;
    int sub = t & 1;
    const float4* yb = (const float4*)yin;
    const float4* self = yb + (size_t)i * 10 + sub * 5;
    float4 a0 = self[0], a1 = self[1], a2 = self[2], a3 = self[3], a4 = self[4];

    int e = row_ptr[i], end = row_ptr[i + 1];
    for (; e + 2 <= end; e += 2) {
        int s0 = csr_src[e], s1 = csr_src[e + 1];
        const float4* p0 = yb + (size_t)s0 * 10 + sub * 5;
        const float4* p1 = yb + (size_t)s1 * 10 + sub * 5;
        float4 v00 = p0[0], v01 = p0[1], v02 = p0[2], v03 = p0[3], v04 = p0[4];
        float4 v10 = p1[0], v11 = p1[1], v12 = p1[2], v13 = p1[3], v14 = p1[4];
        a0.x += v00.x + v10.x; a0.y += v00.y + v10.y; a0.z += v00.z + v10.z; a0.w += v00.w + v10.w;
        a1.x += v01.x + v11.x; a1.y += v01.y + v11.y; a1.z += v01.z + v11.z; a1.w += v01.w + v11.w;
        a2.x += v02.x + v12.x; a2.y += v02.y + v12.y; a2.z += v02.z + v12.z; a2.w += v02.w + v12.w;
        a3.x += v03.x + v13.x; a3.y += v03.y + v13.y; a3.z += v03.z + v13.z; a3.w += v03.w + v13.w;
        a4.x += v04.x + v14.x; a4.y += v04.y + v14.y; a4.z += v04.z + v14.z; a4.w += v04.w + v14.w;
    }
    if (e < end) {
        int s0 = csr_src[e];
        const float4* p0 = yb + (size_t)s0 * 10 + sub * 5;
        float4 v00 = p0[0], v01 = p0[1], v02 = p0[2], v03 = p0[3], v04 = p0[4];
        a0.x += v00.x; a0.y += v00.y; a0.z += v00.z; a0.w += v00.w;
        a1.x += v01.x; a1.y += v01.y; a1.z += v01.z; a1.w += v01.w;
        a2.x += v02.x; a2.y += v02.y; a2.z += v02.z; a2.w += v02.w;
        a3.x += v03.x; a3.y += v03.y; a3.z += v03.z; a3.w += v03.w;
        a4.x += v04.x; a4.y += v04.y; a4.z += v04.z; a4.w += v04.w;
    }

    float di = dinv[i];
    const float4* b4 = (const float4*)bias + sub * 5;
    float4 l[5];
    float4 av[5] = {a0, a1, a2, a3, a4};
    float m = -INFINITY;
#pragma unroll
    for (int r = 0; r < 5; ++r) {
        float4 b = b4[r];
        l[r].x = av[r].x * di + b.x;
        l[r].y = av[r].y * di + b.y;
        l[r].z = av[r].z * di + b.z;
        l[r].w = av[r].w * di + b.w;
        m = fmaxf(m, fmaxf(fmaxf(l[r].x, l[r].y), fmaxf(l[r].z, l[r].w)));
    }
    m = fmaxf(m, __shfl_xor(m, 1));     // pair (2i, 2i+1) shares a wave
    float s = 0.f;
#pragma unroll
    for (int r = 0; r < 5; ++r) {
        s += __expf(l[r].x - m) + __expf(l[r].y - m)
           + __expf(l[r].z - m) + __expf(l[r].w - m);
    }
    s += __shfl_xor(s, 1);
    float lse = __logf(s) + m;

    float4* o = (float4*)out + (size_t)i * 10 + sub * 5;
#pragma unroll
    for (int r = 0; r < 5; ++r) {
        o[r] = make_float4(l[r].x - lse, l[r].y - lse, l[r].z - lse, l[r].w - lse);
    }
}

// ================= launch =================

extern "C" void kernel_launch(void* const* d_in, const int* in_sizes, int n_in,
                              void* d_out, int out_size, void* d_ws, size_t ws_size,
                              hipStream_t stream) {
    const float* x   = (const float*)d_in[0];
    const int*   ei  = (const int*)d_in[1];
    const float* W   = (const float*)d_in[2];
    const float* b   = (const float*)d_in[3];
    float*       out = (float*)d_out;

    const int* esrc = ei;
    const int* edst = ei + N_EDGES;

    // workspace layout (4-byte elems, 16B-aligned sections)
    int*   deg     = (int*)d_ws;                       // NPAD
    int*   row_ptr = deg + NPAD;                       // NPAD (covers N_NODES+1)
    int*   cursor  = row_ptr + NPAD;                   // NPAD
    int*   blksum  = cursor + NPAD;                    // 128
    int*   csr_src = blksum + 128;                     // 600064
    float* dinv    = (float*)(csr_src + 600064);       // NPAD
    float* u0      = dinv + NPAD;                      // 4,000,000
    float* u1      = u0 + (size_t)N_NODES * N_CLASSES; // 4,000,000

    const int B = 256;
    const int gE = (N_EDGES + B - 1) / B;              // 2344
    const int gG = (2 * N_NODES + B - 1) / B;          // 782 (2 threads/node)

    hipMemsetAsync(deg, 0, NPAD * sizeof(int), stream);
    k_count<<<gE, B, 0, stream>>>(edst, deg);
    k_scan1<<<SCAN_NBLK, B, 0, stream>>>(deg, row_ptr, blksum);
    k_scan2<<<SCAN_NBLK, B, 0, stream>>>(deg, row_ptr, cursor, dinv, blksum);
    k_fill <<<gE, B, 0, stream>>>(esrc, edst, cursor, csr_src);

    k_gemm<<<(N_NODES + 63) / 64, B, 0, stream>>>(x, W, dinv, u0);

    k_gather    <<<gG, B, 0, stream>>>(u0, u1, dinv, row_ptr, csr_src);
    k_gather_out<<<gG, B, 0, stream>>>(u1, out, dinv, row_ptr, csr_src, b);
}

// Round 5
// 156.652 us; speedup vs baseline: 13.5644x; 1.1443x over previous
//
#include <hip/hip_runtime.h>

#define N_NODES   100000
#define N_EDGES   600000
#define D_FEAT    128
#define N_CLASSES 40

#define NPAD      100352            // N_NODES padded to 1024 multiple
#define SCAN_NBLK (NPAD / 1024)     // 98

// ================= CSR build =================

__global__ void k_zero(int4* __restrict__ deg4) {
    int i = blockIdx.x * blockDim.x + threadIdx.x;
    if (i < NPAD / 4) deg4[i] = make_int4(0, 0, 0, 0);
}

__global__ void k_count(const int* __restrict__ edst, int* __restrict__ deg) {
    int e = blockIdx.x * blockDim.x + threadIdx.x;
    if (e < N_EDGES) atomicAdd(&deg[edst[e]], 1);
}

// phase 1: per-block exclusive scan (1024 elems/block), local prefixes -> row_ptr
__global__ __launch_bounds__(256) void k_scan1(const int* __restrict__ deg,
                                               int* __restrict__ row_ptr,
                                               int* __restrict__ blksum) {
    __shared__ int wsum[4];
    int t = threadIdx.x;
    int lane = t & 63, w = t >> 6;
    int base = blockIdx.x * 1024 + t * 4;
    int4 v = *(const int4*)(deg + base);
    int s0 = v.x, s1 = s0 + v.y, s2 = s1 + v.z, s3 = s2 + v.w;
    int inc = s3;
#pragma unroll
    for (int d = 1; d < 64; d <<= 1) {
        int y = __shfl_up(inc, d, 64);
        if (lane >= d) inc += y;
    }
    if (lane == 63) wsum[w] = inc;
    __syncthreads();
    int woff = 0;
#pragma unroll
    for (int j = 0; j < 3; ++j) woff += (j < w) ? wsum[j] : 0;
    int texcl = woff + inc - s3;
    int4 o;
    o.x = texcl;
    o.y = texcl + s0;
    o.z = texcl + s1;
    o.w = texcl + s2;
    *(int4*)(row_ptr + base) = o;
    if (t == 255) blksum[blockIdx.x] = woff + inc;   // block total
}

// phase 2: add block offsets in place; emit cursor + dinv
__global__ __launch_bounds__(256) void k_scan2(const int* __restrict__ deg,
                                               int* __restrict__ row_ptr,
                                               int* __restrict__ cursor,
                                               float* __restrict__ dinv,
                                               const int* __restrict__ blksum) {
    __shared__ int s[SCAN_NBLK];
    int t = threadIdx.x;
    int blk = blockIdx.x;
    if (t < SCAN_NBLK) s[t] = blksum[t];
    __syncthreads();
    int off = 0;
    for (int j = 0; j < blk; ++j) off += s[j];
    int base = blk * 1024 + t * 4;
    int4 v = *(int4*)(row_ptr + base);
    v.x += off; v.y += off; v.z += off; v.w += off;
    *(int4*)(row_ptr + base) = v;
    *(int4*)(cursor + base) = v;
    int4 d = *(const int4*)(deg + base);
    float4 di;
    di.x = rsqrtf((float)(d.x + 1));
    di.y = rsqrtf((float)(d.y + 1));
    di.z = rsqrtf((float)(d.z + 1));
    di.w = rsqrtf((float)(d.w + 1));
    *(float4*)(dinv + base) = di;
    // row_ptr[N_NODES] = 600000 falls out of the scan (deg padding is zero)
}

__global__ void k_fill(const int* __restrict__ esrc, const int* __restrict__ edst,
                       int* __restrict__ cursor, int* __restrict__ csr_src) {
    int e = blockIdx.x * blockDim.x + threadIdx.x;
    if (e < N_EDGES) {
        int d = edst[e];
        int pos = atomicAdd(&cursor[d], 1);
        csr_src[pos] = esrc[e];
    }
}

// ================= u0 = (x @ W^T) * dinv[node] =================
// 256 threads/block = 64 quads; each quad (4 threads, 10 classes each)
// computes 4 consecutive nodes -> 10 LDS reads feed 160 FMAs per d4 iter.

#define WROW 132

__global__ __launch_bounds__(256) void k_gemm(const float* __restrict__ x,
                                              const float* __restrict__ W,
                                              const float* __restrict__ dinv,
                                              float* __restrict__ y) {
    __shared__ float Wl[N_CLASSES][WROW];
    int t = threadIdx.x;

    for (int f = t; f < N_CLASSES * (D_FEAT / 4); f += 256) {
        int c = f >> 5, d4 = f & 31;
        float4 w = ((const float4*)W)[f];
        *(float4*)&Wl[c][d4 * 4] = w;
    }
    __syncthreads();

    int quad = t >> 2;                    // 0..63
    int sub  = t & 3;
    int c0   = sub * 10;
    int n0   = blockIdx.x * 256 + quad * 4;   // N_NODES % 4 == 0: quad all-or-nothing
    if (n0 >= N_NODES) return;

    const float4* xp = (const float4*)(x + (size_t)n0 * D_FEAT);  // rows n0..n0+3

    float acc[4][10];
#pragma unroll
    for (int k = 0; k < 4; ++k)
#pragma unroll
        for (int j = 0; j < 10; ++j) acc[k][j] = 0.f;

    for (int d4 = 0; d4 < D_FEAT / 4; ++d4) {
        float4 x0 = xp[d4];
        float4 x1 = xp[32 + d4];
        float4 x2 = xp[64 + d4];
        float4 x3 = xp[96 + d4];
#pragma unroll
        for (int j = 0; j < 10; ++j) {
            float4 wv = *(const float4*)&Wl[c0 + j][d4 * 4];
            acc[0][j] += x0.x * wv.x + x0.y * wv.y + x0.z * wv.z + x0.w * wv.w;
            acc[1][j] += x1.x * wv.x + x1.y * wv.y + x1.z * wv.z + x1.w * wv.w;
            acc[2][j] += x2.x * wv.x + x2.y * wv.y + x2.z * wv.z + x2.w * wv.w;
            acc[3][j] += x3.x * wv.x + x3.y * wv.y + x3.z * wv.z + x3.w * wv.w;
        }
    }

#pragma unroll
    for (int k = 0; k < 4; ++k) {
        float di = dinv[n0 + k];
        float* o = y + (size_t)(n0 + k) * N_CLASSES + c0;
#pragma unroll
        for (int j = 0; j < 10; ++j) o[j] = acc[k][j] * di;
    }
}

// ================= CSR gather propagation on u (4 threads/node) =================
// u_out[d] = dinv[d]^2 * ( u_in[d] + sum_{s in N(d)} u_in[s] )
// thread role: sub = feature half (bit0), par = edge parity (bit1).

__global__ __launch_bounds__(256) void k_gather(const float* __restrict__ yin,
                                                float* __restrict__ yout,
                                                const float* __restrict__ dinv,
                                                const int* __restrict__ row_ptr,
                                                const int* __restrict__ csr_src) {
    int t = blockIdx.x * blockDim.x + threadIdx.x;
    int i = t >> 2;
    if (i >= N_NODES) return;
    int sub = t & 1;
    int par = (t >> 1) & 1;
    const float4* yb = (const float4*)yin;

    float4 a0, a1, a2, a3, a4;
    if (par == 0) {
        const float4* self = yb + (size_t)i * 10 + sub * 5;
        a0 = self[0]; a1 = self[1]; a2 = self[2]; a3 = self[3]; a4 = self[4];
    } else {
        a0 = a1 = a2 = a3 = a4 = make_float4(0.f, 0.f, 0.f, 0.f);
    }

    int e = row_ptr[i] + par, end = row_ptr[i + 1];
    for (; e < end; e += 2) {
        int s = csr_src[e];
        const float4* p = yb + (size_t)s * 10 + sub * 5;
        float4 v0 = p[0], v1 = p[1], v2 = p[2], v3 = p[3], v4 = p[4];
        a0.x += v0.x; a0.y += v0.y; a0.z += v0.z; a0.w += v0.w;
        a1.x += v1.x; a1.y += v1.y; a1.z += v1.z; a1.w += v1.w;
        a2.x += v2.x; a2.y += v2.y; a2.z += v2.z; a2.w += v2.w;
        a3.x += v3.x; a3.y += v3.y; a3.z += v3.z; a3.w += v3.w;
        a4.x += v4.x; a4.y += v4.y; a4.z += v4.z; a4.w += v4.w;
    }

    // combine edge-parity partial sums (lanes differ in bit 1)
    a0.x += __shfl_xor(a0.x, 2); a0.y += __shfl_xor(a0.y, 2); a0.z += __shfl_xor(a0.z, 2); a0.w += __shfl_xor(a0.w, 2);
    a1.x += __shfl_xor(a1.x, 2); a1.y += __shfl_xor(a1.y, 2); a1.z += __shfl_xor(a1.z, 2); a1.w += __shfl_xor(a1.w, 2);
    a2.x += __shfl_xor(a2.x, 2); a2.y += __shfl_xor(a2.y, 2); a2.z += __shfl_xor(a2.z, 2); a2.w += __shfl_xor(a2.w, 2);
    a3.x += __shfl_xor(a3.x, 2); a3.y += __shfl_xor(a3.y, 2); a3.z += __shfl_xor(a3.z, 2); a3.w += __shfl_xor(a3.w, 2);
    a4.x += __shfl_xor(a4.x, 2); a4.y += __shfl_xor(a4.y, 2); a4.z += __shfl_xor(a4.z, 2); a4.w += __shfl_xor(a4.w, 2);

    if (par == 0) {
        float di = dinv[i];
        float s2 = di * di;
        float4* o = (float4*)yout + (size_t)i * 10 + sub * 5;
        o[0] = make_float4(a0.x * s2, a0.y * s2, a0.z * s2, a0.w * s2);
        o[1] = make_float4(a1.x * s2, a1.y * s2, a1.z * s2, a1.w * s2);
        o[2] = make_float4(a2.x * s2, a2.y * s2, a2.z * s2, a2.w * s2);
        o[3] = make_float4(a3.x * s2, a3.y * s2, a3.z * s2, a3.w * s2);
        o[4] = make_float4(a4.x * s2, a4.y * s2, a4.z * s2, a4.w * s2);
    }
}

// final round: logits = dinv[d]*v + b, then log_softmax
__global__ __launch_bounds__(256) void k_gather_out(const float* __restrict__ yin,
                                                    float* __restrict__ out,
                                                    const float* __restrict__ dinv,
                                                    const int* __restrict__ row_ptr,
                                                    const int* __restrict__ csr_src,
                                                    const float* __restrict__ bias) {
    int t = blockIdx.x * blockDim.x + threadIdx.x;
    int i = t >> 2;
    if (i >= N_NODES) return;
    int sub = t & 1;
    int par = (t >> 1) & 1;
    const float4* yb = (const float4*)yin;

    float4 a0, a1, a2, a3, a4;
    if (par == 0) {
        const float4* self = yb + (size_t)i * 10 + sub * 5;
        a0 = self[0]; a1 = self[1]; a2 = self[2]; a3 = self[3]; a4 = self[4];
    } else {
        a0 = a1 = a2 = a3 = a4 = make_float4(0.f, 0.f, 0.f, 0.f);
    }

    int e = row_ptr[i] + par, end = row_ptr[i + 1];
    for (; e < end; e += 2) {
        int s = csr_src[e];
        const float4* p = yb + (size_t)s * 10 + sub * 5;
        float4 v0 = p[0], v1 = p[1], v2 = p[2], v3 = p[3], v4 = p[4];
        a0.x += v0.x; a0.y += v0.y; a0.z += v0.z; a0.w += v0.w;
        a1.x += v1.x; a1.y += v1.y; a1.z += v1.z; a1.w += v1.w;
        a2.x += v2.x; a2.y += v2.y; a2.z += v2.z; a2.w += v2.w;
        a3.x += v3.x; a3.y += v3.y; a3.z += v3.z; a3.w += v3.w;
        a4.x += v4.x; a4.y += v4.y; a4.z += v4.z; a4.w += v4.w;
    }

    a0.x += __shfl_xor(a0.x, 2); a0.y += __shfl_xor(a0.y, 2); a0.z += __shfl_xor(a0.z, 2); a0.w += __shfl_xor(a0.w, 2);
    a1.x += __shfl_xor(a1.x, 2); a1.y += __shfl_xor(a1.y, 2); a1.z += __shfl_xor(a1.z, 2); a1.w += __shfl_xor(a1.w, 2);
    a2.x += __shfl_xor(a2.x, 2); a2.y += __shfl_xor(a2.y, 2); a2.z += __shfl_xor(a2.z, 2); a2.w += __shfl_xor(a2.w, 2);
    a3.x += __shfl_xor(a3.x, 2); a3.y += __shfl_xor(a3.y, 2); a3.z += __shfl_xor(a3.z, 2); a3.w += __shfl_xor(a3.w, 2);
    a4.x += __shfl_xor(a4.x, 2); a4.y += __shfl_xor(a4.y, 2); a4.z += __shfl_xor(a4.z, 2); a4.w += __shfl_xor(a4.w, 2);

    float di = dinv[i];
    const float4* b4 = (const float4*)bias + sub * 5;
    float4 av[5] = {a0, a1, a2, a3, a4};
    float4 l[5];
    float m = -INFINITY;
#pragma unroll
    for (int r = 0; r < 5; ++r) {
        float4 b = b4[r];
        l[r].x = av[r].x * di + b.x;
        l[r].y = av[r].y * di + b.y;
        l[r].z = av[r].z * di + b.z;
        l[r].w = av[r].w * di + b.w;
        m = fmaxf(m, fmaxf(fmaxf(l[r].x, l[r].y), fmaxf(l[r].z, l[r].w)));
    }
    m = fmaxf(m, __shfl_xor(m, 1));     // combine feature halves (bit 0)
    float s = 0.f;
#pragma unroll
    for (int r = 0; r < 5; ++r) {
        s += __expf(l[r].x - m) + __expf(l[r].y - m)
           + __expf(l[r].z - m) + __expf(l[r].w - m);
    }
    s += __shfl_xor(s, 1);
    float lse = __logf(s) + m;

    if (par == 0) {
        float4* o = (float4*)out + (size_t)i * 10 + sub * 5;
#pragma unroll
        for (int r = 0; r < 5; ++r) {
            o[r] = make_float4(l[r].x - lse, l[r].y - lse, l[r].z - lse, l[r].w - lse);
        }
    }
}

// ================= launch =================

extern "C" void kernel_launch(void* const* d_in, const int* in_sizes, int n_in,
                              void* d_out, int out_size, void* d_ws, size_t ws_size,
                              hipStream_t stream) {
    const float* x   = (const float*)d_in[0];
    const int*   ei  = (const int*)d_in[1];
    const float* W   = (const float*)d_in[2];
    const float* b   = (const float*)d_in[3];
    float*       out = (float*)d_out;

    const int* esrc = ei;
    const int* edst = ei + N_EDGES;

    // workspace layout (4-byte elems, 16B-aligned sections)
    int*   deg     = (int*)d_ws;                       // NPAD
    int*   row_ptr = deg + NPAD;                       // NPAD (covers N_NODES+1)
    int*   cursor  = row_ptr + NPAD;                   // NPAD
    int*   blksum  = cursor + NPAD;                    // 128
    int*   csr_src = blksum + 128;                     // 600064
    float* dinv    = (float*)(csr_src + 600064);       // NPAD
    float* u0      = dinv + NPAD;                      // 4,000,000
    float* u1      = u0 + (size_t)N_NODES * N_CLASSES; // 4,000,000

    const int B = 256;
    const int gE = (N_EDGES + B - 1) / B;              // 2344
    const int gG = (4 * N_NODES + B - 1) / B;          // 1563 (4 threads/node)

    k_zero <<<(NPAD / 4 + B - 1) / B, B, 0, stream>>>((int4*)deg);
    k_count<<<gE, B, 0, stream>>>(edst, deg);
    k_scan1<<<SCAN_NBLK, B, 0, stream>>>(deg, row_ptr, blksum);
    k_scan2<<<SCAN_NBLK, B, 0, stream>>>(deg, row_ptr, cursor, dinv, blksum);
    k_fill <<<gE, B, 0, stream>>>(esrc, edst, cursor, csr_src);

    k_gemm<<<(N_NODES + 255) / 256, B, 0, stream>>>(x, W, dinv, u0);

    k_gather    <<<gG, B, 0, stream>>>(u0, u1, dinv, row_ptr, csr_src);
    k_gather_out<<<gG, B, 0, stream>>>(u1, out, dinv, row_ptr, csr_src, b);
}